// Round 19
// baseline (118.039 us; speedup 1.0000x reference)
//
#include <hip/hip_runtime.h>
#include <hip/hip_bf16.h>
#include <math.h>

typedef __bf16 bf16;
typedef __bf16 bf16x8 __attribute__((ext_vector_type(8)));
typedef float f32x4 __attribute__((ext_vector_type(4)));
typedef unsigned int u32x2 __attribute__((ext_vector_type(2)));

constexpr int B = 4, S = 2048, E = 1024, H = 16, HD = 64;

// 0.125 (1/sqrt(64)) * log2(e): scores in log2 domain -> raw v_exp_f32
constexpr float QSCALE = 0.125f * 1.44269504088896340736f;
// defer-max threshold (T13): 8 nats in log2 domain
constexpr float DTHR = 11.5f;

static __device__ __forceinline__ float exp2_fast(float x) {
#if __has_builtin(__builtin_amdgcn_exp2f)
    return __builtin_amdgcn_exp2f(x);
#else
    float r; asm("v_exp_f32 %0, %1" : "=v"(r) : "v"(x)); return r;
#endif
}

static __device__ __forceinline__ unsigned pk_bf16(float a, float b) {
    union { bf16 h[2]; unsigned u; } r;
    r.h[0] = (bf16)a; r.h[1] = (bf16)b;
    return r.u;
}

// 3-input max (clang fuses nested fmaxf to v_max3_f32 — T17)
static __device__ __forceinline__ float max3(float a, float b, float c) {
    return fmaxf(fmaxf(a, b), c);
}

// async global->LDS DMA, 16B/lane (block-wide staging only — measured win in
// out_gemm/qkv W-tile; measured regression in attn's wave-sliced staging).
static __device__ __forceinline__ void gl16(const void* g, void* l) {
    __builtin_amdgcn_global_load_lds(
        (__attribute__((address_space(1))) void*)g,
        (__attribute__((address_space(3))) void*)l,
        16, 0, 0);
}

// ---------------------------------------------------------------------------
// Kernel 0: fused weight prep.
// ---------------------------------------------------------------------------
__global__ __launch_bounds__(256) void prep_weights(
    const float* __restrict__ Wq, const float* __restrict__ Wk,
    const float* __restrict__ Wv, const float* __restrict__ Wp,
    bf16* __restrict__ Wt, bf16* __restrict__ Wpt)
{
    __shared__ float t[64][65];
    const int tid = threadIdx.x;
    const int x = blockIdx.x, y = blockIdx.y;
    if (y < 3) {
        const int h = x, p = y;
        const float* W = (p == 0) ? Wq : (p == 1) ? Wk : Wv;
        const float scale = (p == 0) ? QSCALE : 1.0f;
        #pragma unroll
        for (int i = 0; i < 16; ++i) {
            int idx = tid + i * 256;
            int d = idx >> 6, e = idx & 63;
            t[d][e] = W[(size_t)h * 4096 + d * 64 + e];
        }
        __syncthreads();
        bf16* dst = Wt + ((size_t)p * H + h) * 4096;
        #pragma unroll
        for (int i = 0; i < 16; ++i) {
            int idx = tid + i * 256;
            int e = idx >> 6, d = idx & 63;
            dst[e * 64 + d] = (bf16)(t[d][e] * scale);
        }
    } else {
        const int k0 = (y - 3) * 64, n0 = x * 64;
        #pragma unroll
        for (int i = 0; i < 16; ++i) {
            int idx = tid + i * 256;
            int r = idx >> 6, c = idx & 63;
            t[r][c] = Wp[(size_t)(k0 + r) * E + n0 + c];
        }
        __syncthreads();
        #pragma unroll
        for (int i = 0; i < 16; ++i) {
            int idx = tid + i * 256;
            int r = idx >> 6, c = idx & 63;
            Wpt[(size_t)(n0 + r) * E + k0 + c] = (bf16)t[c][r];
        }
    }
}

// ---------------------------------------------------------------------------
// Kernel 1: QKV projections via MFMA (verified 16x16x32 contract).
// W tile staged via gl16 (block-wide bf16, pre-swizzled src — measured R14).
// ---------------------------------------------------------------------------
__global__ __launch_bounds__(256) void qkv_proj(
    const float* __restrict__ xq, const float* __restrict__ xk, const float* __restrict__ xv,
    const bf16* __restrict__ Wt,
    const float* __restrict__ bq, const float* __restrict__ bk, const float* __restrict__ bv,
    bf16* __restrict__ Qb, bf16* __restrict__ Kb, bf16* __restrict__ Vt)
{
    const int b = blockIdx.z, h = blockIdx.y, s0 = blockIdx.x * 128;
    const int tid = threadIdx.x;
    const int w = tid >> 6, l = tid & 63;
    const int l16 = l & 15, lg = l >> 4;
    const size_t bh = (size_t)b * H + h;

    __shared__ __align__(16) bf16 xs[128][64];
    __shared__ __align__(16) bf16 Wl[64][64];
    __shared__ __align__(16) bf16 ts[10240];

    const int r8 = l >> 3;
    const int wchunk = ((l & 7) ^ r8) * 8;   // lane-constant swizzled chunk

    for (int p = 0; p < 3; ++p) {
        const float* x    = (p == 0) ? xq : (p == 1) ? xk : xv;
        const float* bias = (p == 0) ? bq : (p == 1) ? bk : bv;
        const float  bsc  = (p == 0) ? QSCALE : 1.0f;

        __syncthreads();
        // ---- W^T [64][64] bf16 via gl16 (2 issues/thread) ----
        const bf16* wsrc = Wt + ((size_t)p * H + h) * 4096;
        #pragma unroll
        for (int i = 0; i < 2; ++i) {
            const int rb = 8 * (w + 4 * i);
            gl16(wsrc + (size_t)(rb + r8) * 64 + wchunk, &Wl[rb][0]);
        }
        // ---- stage x tile [128][64] fp32 -> bf16 swizzled (reg path) ----
        #pragma unroll
        for (int i = 0; i < 4; ++i) {
            int idx = tid + i * 256;
            int r = idx >> 3, g = idx & 7;
            const float* src = &x[((size_t)b * S + s0 + r) * E + h * 64 + g * 8];
            float4 f0 = *(const float4*)src;
            float4 f1 = *(const float4*)(src + 4);
            union { bf16 h8[8]; uint4 u; } pk;
            pk.h8[0] = (bf16)f0.x; pk.h8[1] = (bf16)f0.y;
            pk.h8[2] = (bf16)f0.z; pk.h8[3] = (bf16)f0.w;
            pk.h8[4] = (bf16)f1.x; pk.h8[5] = (bf16)f1.y;
            pk.h8[6] = (bf16)f1.z; pk.h8[7] = (bf16)f1.w;
            *(uint4*)&xs[r][(g ^ (r & 7)) * 8] = pk.u;
        }
        __syncthreads();

        if (p < 2) {
            float bcol[4];
            #pragma unroll
            for (int ei = 0; ei < 4; ++ei)
                bcol[ei] = bias[h * 64 + ei * 16 + l16] * bsc;
            #pragma unroll
            for (int st = 0; st < 2; ++st) {
                const int srow = w * 32 + st * 16 + l16;
                bf16x8 a0 = *(const bf16x8*)&xs[srow][((lg    ) ^ (srow & 7)) * 8];
                bf16x8 a1 = *(const bf16x8*)&xs[srow][((4 + lg) ^ (srow & 7)) * 8];
                #pragma unroll
                for (int ei = 0; ei < 4; ++ei) {
                    const int erow = ei * 16 + l16;
                    bf16x8 b0 = *(const bf16x8*)&Wl[erow][((lg    ) ^ (erow & 7)) * 8];
                    bf16x8 b1 = *(const bf16x8*)&Wl[erow][((4 + lg) ^ (erow & 7)) * 8];
                    f32x4 acc = {0.f, 0.f, 0.f, 0.f};
                    acc = __builtin_amdgcn_mfma_f32_16x16x32_bf16(a0, b0, acc, 0, 0, 0);
                    acc = __builtin_amdgcn_mfma_f32_16x16x32_bf16(a1, b1, acc, 0, 0, 0);
                    #pragma unroll
                    for (int r = 0; r < 4; ++r)
                        ts[(w * 32 + st * 16 + 4 * lg + r) * 80 + ei * 16 + l16] =
                            (bf16)(acc[r] + bcol[ei]);
                }
            }
            __syncthreads();
            bf16* out = (p == 0) ? Qb : Kb;
            #pragma unroll
            for (int i = 0; i < 4; ++i) {
                int idx = tid + i * 256;
                int r = idx >> 3, g = idx & 7;
                uint4 v = *(const uint4*)&ts[r * 80 + g * 8];
                *(uint4*)(out + (bh * S + s0 + r) * 64 + g * 8) = v;
            }
        } else {
            float brow[4];
            #pragma unroll
            for (int r = 0; r < 4; ++r)
                brow[r] = bias[h * 64 + w * 16 + 4 * lg + r];
            const int erow = w * 16 + l16;
            bf16x8 a0 = *(const bf16x8*)&Wl[erow][((lg    ) ^ (erow & 7)) * 8];
            bf16x8 a1 = *(const bf16x8*)&Wl[erow][((4 + lg) ^ (erow & 7)) * 8];
            #pragma unroll
            for (int st = 0; st < 8; ++st) {
                const int srow = st * 16 + l16;
                bf16x8 b0 = *(const bf16x8*)&xs[srow][((lg    ) ^ (srow & 7)) * 8];
                bf16x8 b1 = *(const bf16x8*)&xs[srow][((4 + lg) ^ (srow & 7)) * 8];
                f32x4 acc = {0.f, 0.f, 0.f, 0.f};
                acc = __builtin_amdgcn_mfma_f32_16x16x32_bf16(a0, b0, acc, 0, 0, 0);
                acc = __builtin_amdgcn_mfma_f32_16x16x32_bf16(a1, b1, acc, 0, 0, 0);
                #pragma unroll
                for (int r = 0; r < 4; ++r)
                    ts[(w * 16 + 4 * lg + r) * 136 + st * 16 + l16] =
                        (bf16)(acc[r] + brow[r]);
            }
            __syncthreads();
            #pragma unroll
            for (int i = 0; i < 4; ++i) {
                int idx = tid + i * 256;
                int r = idx >> 4, g = idx & 15;
                uint4 v = *(const uint4*)&ts[r * 136 + g * 8];
                *(uint4*)(Vt + (bh * 64 + r) * S + s0 + g * 8) = v;
            }
        }
    }
}

// ---------------------------------------------------------------------------
// Kernel 3: causal flash attention — R17 structure (measured 65.4 us) + T17
// v_max3 tree (15 -> 7 VALU ops, semantics identical).
// ---------------------------------------------------------------------------
__global__ __launch_bounds__(512) void attn(
    const bf16* __restrict__ Qb, const bf16* __restrict__ Kb,
    const bf16* __restrict__ Vt, bf16* __restrict__ ctx)
{
    const int lin = blockIdx.y * 8 + blockIdx.x;   // 0..1023
    const int bh  = lin & 63;                      // b*H + h
    const int qt  = 15 - (lin >> 6);               // heavy tiles dispatch first
    const int b = bh >> 4, h = bh & 15;
    const int tid = threadIdx.x;
    const int w = tid >> 6;          // warp 0..7
    const int l = tid & 63;
    const int l16 = l & 15, lg = l >> 4;

    __shared__ __align__(16) bf16 Kl[2][64][64];
    __shared__ __align__(16) bf16 Vl[2][64][64];
    __shared__ __align__(16) bf16 Pl[8][16][72];

    const bf16* Qp = Qb + (size_t)bh * S * 64;
    const bf16* Kp = Kb + (size_t)bh * S * 64;
    const bf16* Vp = Vt + (size_t)bh * 64 * S;

    const int str = tid >> 3;
    const int stc = tid & 7;
    const int sws = (stc ^ (str & 7)) * 8;

    int foff0[4], foff1[4];
    #pragma unroll
    for (int s = 0; s < 4; ++s) {
        foff0[s] = (16 * s + l16) * 64 + ((lg    ) ^ (l16 & 7)) * 8;
        foff1[s] = (16 * s + l16) * 64 + ((4 + lg) ^ (l16 & 7)) * 8;
    }
    bf16* Plw = &Pl[w][0][0];
    const int pwr = l16 * 72 + 4 * lg;         // P write col base (s adds 16s)
    const int prd = l16 * 72 + 8 * lg;         // P read offset (second +32)

    const bf16 one_ = (bf16)1.0f;
    const bf16x8 ones = {one_, one_, one_, one_, one_, one_, one_, one_};

    const int qw0  = qt * 128 + w * 16;
    const int qabs = qw0 + l16;
    const int nt   = 2 * qt + 2;

    bf16x8 qf0 = *(const bf16x8*)(Qp + (size_t)qabs * 64 + lg * 8);
    bf16x8 qf1 = *(const bf16x8*)(Qp + (size_t)qabs * 64 + 32 + lg * 8);

    f32x4 o[4] = {};
    float m_run = -1e30f, l_run = 0.f;

    {
        uint4 kreg = *(const uint4*)(Kp + (size_t)str * 64 + stc * 8);
        uint4 vreg = *(const uint4*)(Vp + (size_t)str * S + stc * 8);
        *(uint4*)&Kl[0][str][sws] = kreg;
        *(uint4*)&Vl[0][str][sws] = vreg;
    }
    int cur = 0;
    for (int t = 0; t < nt; ++t) {
        __syncthreads();
        const bool pfv = (t + 1 < nt);
        uint4 kreg, vreg;
        if (pfv) {                         // issue-early (T14)
            const int kv1 = (t + 1) * 64;
            kreg = *(const uint4*)(Kp + (size_t)(kv1 + str) * 64 + stc * 8);
            vreg = *(const uint4*)(Vp + (size_t)str * S + kv1 + stc * 8);
        }
        const int kv0 = t * 64;
        if (kv0 < qw0 + 16) {              // warp-uniform causal skip
            const bf16* Kbase = &Kl[cur][0][0];
            const bf16* Vbase = &Vl[cur][0][0];

            // ---- QK^T (swapped): S^T[kv][q], 8 MFMAs ----
            float p[16];
            __builtin_amdgcn_s_setprio(1);
            #pragma unroll
            for (int s = 0; s < 4; ++s) {
                f32x4 sc = {0.f, 0.f, 0.f, 0.f};
                bf16x8 ka = *(const bf16x8*)(Kbase + foff0[s]);
                bf16x8 kb = *(const bf16x8*)(Kbase + foff1[s]);
                sc = __builtin_amdgcn_mfma_f32_16x16x32_bf16(ka, qf0, sc, 0, 0, 0);
                sc = __builtin_amdgcn_mfma_f32_16x16x32_bf16(kb, qf1, sc, 0, 0, 0);
                p[4 * s + 0] = sc[0]; p[4 * s + 1] = sc[1];
                p[4 * s + 2] = sc[2]; p[4 * s + 3] = sc[3];
            }
            __builtin_amdgcn_s_setprio(0);

            // ---- causal mask (only warp-diagonal tiles) ----
            if (kv0 + 63 > qw0) {
                #pragma unroll
                for (int i = 0; i < 16; ++i) {
                    const int kvloc = 16 * (i >> 2) + 4 * lg + (i & 3);
                    if (kv0 + kvloc > qabs) p[i] = -1e30f;
                }
            }

            // ---- online softmax: lane-local defer-max, v_max3 tree ----
            const float a0 = max3(p[0],  p[1],  p[2]);
            const float a1 = max3(p[3],  p[4],  p[5]);
            const float a2 = max3(p[6],  p[7],  p[8]);
            const float a3 = max3(p[9],  p[10], p[11]);
            const float a4 = max3(p[12], p[13], p[14]);
            const float lmx = fmaxf(max3(a0, a1, a2), max3(a3, a4, p[15]));
            if (!__all(lmx <= m_run + DTHR)) {     // rare: rescale path
                float mx = fmaxf(lmx, __shfl_xor(lmx, 16));
                mx = fmaxf(mx, __shfl_xor(mx, 32));
                const float m_new = fmaxf(m_run, mx);
                const float corr = exp2_fast(m_run - m_new);
                l_run *= corr;
                #pragma unroll
                for (int ds = 0; ds < 4; ++ds) {
                    o[ds][0] *= corr; o[ds][1] *= corr;
                    o[ds][2] *= corr; o[ds][3] *= corr;
                }
                m_run = m_new;
            }
            #pragma unroll
            for (int i = 0; i < 16; ++i) p[i] = exp2_fast(p[i] - m_run);

            // ---- P -> per-warp LDS (bf16), then read PV B-frags ----
            #pragma unroll
            for (int s = 0; s < 4; ++s) {
                u32x2 pw;
                pw[0] = pk_bf16(p[4 * s + 0], p[4 * s + 1]);
                pw[1] = pk_bf16(p[4 * s + 2], p[4 * s + 3]);
                *(u32x2*)(Plw + pwr + 16 * s) = pw;
            }
            asm volatile("s_waitcnt lgkmcnt(0)" ::: "memory");
            bf16x8 pf0 = *(const bf16x8*)(Plw + prd);
            bf16x8 pf1 = *(const bf16x8*)(Plw + prd + 32);

            // ---- PV (swapped) + ones-row sum: 8 + 2 MFMAs ----
            __builtin_amdgcn_s_setprio(1);
            f32x4 o5 = {0.f, 0.f, 0.f, 0.f};
            o5 = __builtin_amdgcn_mfma_f32_16x16x32_bf16(ones, pf0, o5, 0, 0, 0);
            o5 = __builtin_amdgcn_mfma_f32_16x16x32_bf16(ones, pf1, o5, 0, 0, 0);
            #pragma unroll
            for (int ds = 0; ds < 4; ++ds) {
                bf16x8 v0 = *(const bf16x8*)(Vbase + foff0[ds]);
                bf16x8 v1 = *(const bf16x8*)(Vbase + foff1[ds]);
                o[ds] = __builtin_amdgcn_mfma_f32_16x16x32_bf16(v0, pf0, o[ds], 0, 0, 0);
                o[ds] = __builtin_amdgcn_mfma_f32_16x16x32_bf16(v1, pf1, o[ds], 0, 0, 0);
            }
            __builtin_amdgcn_s_setprio(0);
            l_run += o5[0];               // all 4 regs identical (ones rows)
        }
        if (pfv) {                         // write-late into other buffer
            *(uint4*)&Kl[cur ^ 1][str][sws] = kreg;
            *(uint4*)&Vl[cur ^ 1][str][sws] = vreg;
        }
        cur ^= 1;
    }

    const float il = 1.0f / l_run;
    bf16* crow = ctx + ((size_t)b * S + qabs) * E + h * 64;
    #pragma unroll
    for (int ds = 0; ds < 4; ++ds) {
        u32x2 pw;
        pw[0] = pk_bf16(o[ds][0] * il, o[ds][1] * il);
        pw[1] = pk_bf16(o[ds][2] * il, o[ds][3] * il);
        *(u32x2*)(crow + 16 * ds + 4 * lg) = pw;
    }
}

// ---------------------------------------------------------------------------
// Kernel 4: out = ctx[8192x1024] @ Wp[1024x1024] + bp, fp32 out.
// R18 2-phase gl16 dbuf + NEW: LDS-staged C epilogue. The K-loop's dead
// Al/Bl LDS (no outstanding DMA; barrier-fenced) is reused as a padded
// fp32 [128][132] stage; final write = 16 dense float4 stores/thread
// (full 128B lines -> kills the ~2.75x partial-line write amplification).
// ---------------------------------------------------------------------------
__global__ __launch_bounds__(256) void out_gemm(
    const bf16* __restrict__ A, const bf16* __restrict__ Bt,
    const float* __restrict__ bp, float* __restrict__ C)
{
    const int lin = blockIdx.y * 8 + blockIdx.x;
    const int c   = lin & 7;
    const int k   = lin >> 3;
    const int n0  = (k & 7) * 128;
    const int m0  = (((k >> 3) << 3) | c) * 128;
    const int tid = threadIdx.x;
    const int w = tid >> 6, l = tid & 63;
    const int l16 = l & 15, lg = l >> 4;
    const int wm = w >> 1, wn = w & 1;

    __shared__ __align__(16) char smem[131072];      // 128 KB, aliased
    bf16* AlB = (bf16*)smem;                          // [2][128][64]
    bf16* BlB = (bf16*)(smem + 65536);                // [2][128][64]
    float* Cst = (float*)smem;                        // [128][132] (67.6 KB)

    f32x4 acc[4][4] = {};

    const int r8 = l >> 3;
    const int chunk = ((l & 7) ^ r8) * 8;

    // prologue: DMA tile k0=0 into buffer 0
    #pragma unroll
    for (int i = 0; i < 4; ++i) {
        const int rb = 8 * w + 32 * i;
        gl16(A  + (size_t)(m0 + rb + r8) * E + chunk, AlB + rb * 64);
        gl16(Bt + (size_t)(n0 + rb + r8) * E + chunk, BlB + rb * 64);
    }

    int cur = 0;
    for (int k0 = 0; k0 < E; k0 += 64) {
        __syncthreads();                    // buf[cur] DMA drained (vmcnt 0)
        if (k0 + 64 < E) {                  // DMA next tile into buf[cur^1]
            #pragma unroll
            for (int i = 0; i < 4; ++i) {
                const int rb = 8 * w + 32 * i;
                gl16(A  + (size_t)(m0 + rb + r8) * E + k0 + 64 + chunk,
                     AlB + (cur ^ 1) * 8192 + rb * 64);
                gl16(Bt + (size_t)(n0 + rb + r8) * E + k0 + 64 + chunk,
                     BlB + (cur ^ 1) * 8192 + rb * 64);
            }
        }
        #pragma unroll
        for (int ks = 0; ks < 2; ++ks) {
            bf16x8 af[4], bfr[4];
            #pragma unroll
            for (int mi = 0; mi < 4; ++mi) {
                int r = wm * 64 + mi * 16 + l16;
                af[mi] = *(const bf16x8*)(AlB + cur * 8192 + r * 64 +
                                          ((ks * 4 + lg) ^ (r & 7)) * 8);
            }
            #pragma unroll
            for (int ni = 0; ni < 4; ++ni) {
                int r = wn * 64 + ni * 16 + l16;
                bfr[ni] = *(const bf16x8*)(BlB + cur * 8192 + r * 64 +
                                           ((ks * 4 + lg) ^ (r & 7)) * 8);
            }
            #pragma unroll
            for (int mi = 0; mi < 4; ++mi)
                #pragma unroll
                for (int ni = 0; ni < 4; ++ni)
                    acc[mi][ni] = __builtin_amdgcn_mfma_f32_16x16x32_bf16(
                        af[mi], bfr[ni], acc[mi][ni], 0, 0, 0);
        }
        cur ^= 1;
    }

    // ---- epilogue: acc -> LDS stage (bias fused), then dense float4 out ----
    __syncthreads();                        // all ds_reads done; no DMA pending
    #pragma unroll
    for (int ni = 0; ni < 4; ++ni) {
        const int col = wn * 64 + ni * 16 + l16;
        const float bias = bp[n0 + col];
        #pragma unroll
        for (int mi = 0; mi < 4; ++mi) {
            #pragma unroll
            for (int e = 0; e < 4; ++e) {
                const int row = wm * 64 + mi * 16 + 4 * lg + e;
                Cst[row * 132 + col] = acc[mi][ni][e] + bias;
            }
        }
    }
    __syncthreads();
    #pragma unroll
    for (int i = 0; i < 16; ++i) {
        const int F = i * 256 + tid;        // float4 index 0..4095
        const int row = F >> 5, c4 = (F & 31) * 4;
        float4 v = *(const float4*)&Cst[row * 132 + c4];
        *(float4*)&C[(size_t)(m0 + row) * E + n0 + c4] = v;
    }
}

// ---------------------------------------------------------------------------
extern "C" void kernel_launch(void* const* d_in, const int* in_sizes, int n_in,
                              void* d_out, int out_size, void* d_ws, size_t ws_size,
                              hipStream_t stream)
{
    const float* xq = (const float*)d_in[0];
    const float* xk = (const float*)d_in[1];
    const float* xv = (const float*)d_in[2];
    const float* Wq = (const float*)d_in[3];
    const float* bq = (const float*)d_in[4];
    const float* Wk = (const float*)d_in[5];
    const float* bk = (const float*)d_in[6];
    const float* Wv = (const float*)d_in[7];
    const float* bv = (const float*)d_in[8];
    const float* Wp = (const float*)d_in[9];
    const float* bp = (const float*)d_in[10];
    float* out = (float*)d_out;

    char* ws = (char*)d_ws;
    const size_t sz_bhse = (size_t)B * H * S * HD;
    bf16* Qb  = (bf16*)ws;  ws += sz_bhse * 2;
    bf16* Kb  = (bf16*)ws;  ws += sz_bhse * 2;
    bf16* Vtw = (bf16*)ws;  ws += sz_bhse * 2;
    bf16* ctx = (bf16*)ws;  ws += (size_t)B * S * E * 2;
    bf16* Wpt = (bf16*)ws;  ws += (size_t)E * E * 2;
    bf16* Wt3 = (bf16*)ws;  ws += (size_t)3 * H * HD * HD * 2;

    prep_weights<<<dim3(16, 19), 256, 0, stream>>>(Wq, Wk, Wv, Wp, Wt3, Wpt);
    qkv_proj<<<dim3(S / 128, H, B), 256, 0, stream>>>(xq, xk, xv, Wt3,
                                                      bq, bk, bv, Qb, Kb, Vtw);
    attn<<<dim3(8, 128), 512, 0, stream>>>(Qb, Kb, Vtw, ctx);
    out_gemm<<<dim3(E / 128, (B * S) / 128), 256, 0, stream>>>(ctx, Wpt, bp, out);
}

// Round 20
// 108.889 us; speedup vs baseline: 1.0840x; 1.0840x over previous
//
#include <hip/hip_runtime.h>
#include <hip/hip_bf16.h>
#include <math.h>

typedef __bf16 bf16;
typedef __bf16 bf16x8 __attribute__((ext_vector_type(8)));
typedef float f32x4 __attribute__((ext_vector_type(4)));
typedef unsigned int u32x2 __attribute__((ext_vector_type(2)));

constexpr int B = 4, S = 2048, E = 1024, H = 16, HD = 64;

// 0.125 (1/sqrt(64)) * log2(e): scores in log2 domain -> raw v_exp_f32
constexpr float QSCALE = 0.125f * 1.44269504088896340736f;
// defer-max threshold (T13): 8 nats in log2 domain
constexpr float DTHR = 11.5f;

static __device__ __forceinline__ float exp2_fast(float x) {
#if __has_builtin(__builtin_amdgcn_exp2f)
    return __builtin_amdgcn_exp2f(x);
#else
    float r; asm("v_exp_f32 %0, %1" : "=v"(r) : "v"(x)); return r;
#endif
}

static __device__ __forceinline__ unsigned pk_bf16(float a, float b) {
    union { bf16 h[2]; unsigned u; } r;
    r.h[0] = (bf16)a; r.h[1] = (bf16)b;
    return r.u;
}

// 3-input max (clang fuses nested fmaxf to v_max3_f32 — T17)
static __device__ __forceinline__ float max3(float a, float b, float c) {
    return fmaxf(fmaxf(a, b), c);
}

// async global->LDS DMA, 16B/lane (block-wide staging only — measured win in
// out_gemm/qkv W-tile; measured regression in attn's wave-sliced staging).
static __device__ __forceinline__ void gl16(const void* g, void* l) {
    __builtin_amdgcn_global_load_lds(
        (__attribute__((address_space(1))) void*)g,
        (__attribute__((address_space(3))) void*)l,
        16, 0, 0);
}

// ---------------------------------------------------------------------------
// Kernel 0: fused weight prep.
// ---------------------------------------------------------------------------
__global__ __launch_bounds__(256) void prep_weights(
    const float* __restrict__ Wq, const float* __restrict__ Wk,
    const float* __restrict__ Wv, const float* __restrict__ Wp,
    bf16* __restrict__ Wt, bf16* __restrict__ Wpt)
{
    __shared__ float t[64][65];
    const int tid = threadIdx.x;
    const int x = blockIdx.x, y = blockIdx.y;
    if (y < 3) {
        const int h = x, p = y;
        const float* W = (p == 0) ? Wq : (p == 1) ? Wk : Wv;
        const float scale = (p == 0) ? QSCALE : 1.0f;
        #pragma unroll
        for (int i = 0; i < 16; ++i) {
            int idx = tid + i * 256;
            int d = idx >> 6, e = idx & 63;
            t[d][e] = W[(size_t)h * 4096 + d * 64 + e];
        }
        __syncthreads();
        bf16* dst = Wt + ((size_t)p * H + h) * 4096;
        #pragma unroll
        for (int i = 0; i < 16; ++i) {
            int idx = tid + i * 256;
            int e = idx >> 6, d = idx & 63;
            dst[e * 64 + d] = (bf16)(t[d][e] * scale);
        }
    } else {
        const int k0 = (y - 3) * 64, n0 = x * 64;
        #pragma unroll
        for (int i = 0; i < 16; ++i) {
            int idx = tid + i * 256;
            int r = idx >> 6, c = idx & 63;
            t[r][c] = Wp[(size_t)(k0 + r) * E + n0 + c];
        }
        __syncthreads();
        #pragma unroll
        for (int i = 0; i < 16; ++i) {
            int idx = tid + i * 256;
            int r = idx >> 6, c = idx & 63;
            Wpt[(size_t)(n0 + r) * E + k0 + c] = (bf16)t[c][r];
        }
    }
}

// ---------------------------------------------------------------------------
// Kernel 1: QKV projections via MFMA (verified 16x16x32 contract).
// W tile staged via gl16 (block-wide bf16, pre-swizzled src — measured R14).
// ---------------------------------------------------------------------------
__global__ __launch_bounds__(256) void qkv_proj(
    const float* __restrict__ xq, const float* __restrict__ xk, const float* __restrict__ xv,
    const bf16* __restrict__ Wt,
    const float* __restrict__ bq, const float* __restrict__ bk, const float* __restrict__ bv,
    bf16* __restrict__ Qb, bf16* __restrict__ Kb, bf16* __restrict__ Vt)
{
    const int b = blockIdx.z, h = blockIdx.y, s0 = blockIdx.x * 128;
    const int tid = threadIdx.x;
    const int w = tid >> 6, l = tid & 63;
    const int l16 = l & 15, lg = l >> 4;
    const size_t bh = (size_t)b * H + h;

    __shared__ __align__(16) bf16 xs[128][64];
    __shared__ __align__(16) bf16 Wl[64][64];
    __shared__ __align__(16) bf16 ts[10240];

    const int r8 = l >> 3;
    const int wchunk = ((l & 7) ^ r8) * 8;   // lane-constant swizzled chunk

    for (int p = 0; p < 3; ++p) {
        const float* x    = (p == 0) ? xq : (p == 1) ? xk : xv;
        const float* bias = (p == 0) ? bq : (p == 1) ? bk : bv;
        const float  bsc  = (p == 0) ? QSCALE : 1.0f;

        __syncthreads();
        // ---- W^T [64][64] bf16 via gl16 (2 issues/thread) ----
        const bf16* wsrc = Wt + ((size_t)p * H + h) * 4096;
        #pragma unroll
        for (int i = 0; i < 2; ++i) {
            const int rb = 8 * (w + 4 * i);
            gl16(wsrc + (size_t)(rb + r8) * 64 + wchunk, &Wl[rb][0]);
        }
        // ---- stage x tile [128][64] fp32 -> bf16 swizzled (reg path) ----
        #pragma unroll
        for (int i = 0; i < 4; ++i) {
            int idx = tid + i * 256;
            int r = idx >> 3, g = idx & 7;
            const float* src = &x[((size_t)b * S + s0 + r) * E + h * 64 + g * 8];
            float4 f0 = *(const float4*)src;
            float4 f1 = *(const float4*)(src + 4);
            union { bf16 h8[8]; uint4 u; } pk;
            pk.h8[0] = (bf16)f0.x; pk.h8[1] = (bf16)f0.y;
            pk.h8[2] = (bf16)f0.z; pk.h8[3] = (bf16)f0.w;
            pk.h8[4] = (bf16)f1.x; pk.h8[5] = (bf16)f1.y;
            pk.h8[6] = (bf16)f1.z; pk.h8[7] = (bf16)f1.w;
            *(uint4*)&xs[r][(g ^ (r & 7)) * 8] = pk.u;
        }
        __syncthreads();

        if (p < 2) {
            float bcol[4];
            #pragma unroll
            for (int ei = 0; ei < 4; ++ei)
                bcol[ei] = bias[h * 64 + ei * 16 + l16] * bsc;
            #pragma unroll
            for (int st = 0; st < 2; ++st) {
                const int srow = w * 32 + st * 16 + l16;
                bf16x8 a0 = *(const bf16x8*)&xs[srow][((lg    ) ^ (srow & 7)) * 8];
                bf16x8 a1 = *(const bf16x8*)&xs[srow][((4 + lg) ^ (srow & 7)) * 8];
                #pragma unroll
                for (int ei = 0; ei < 4; ++ei) {
                    const int erow = ei * 16 + l16;
                    bf16x8 b0 = *(const bf16x8*)&Wl[erow][((lg    ) ^ (erow & 7)) * 8];
                    bf16x8 b1 = *(const bf16x8*)&Wl[erow][((4 + lg) ^ (erow & 7)) * 8];
                    f32x4 acc = {0.f, 0.f, 0.f, 0.f};
                    acc = __builtin_amdgcn_mfma_f32_16x16x32_bf16(a0, b0, acc, 0, 0, 0);
                    acc = __builtin_amdgcn_mfma_f32_16x16x32_bf16(a1, b1, acc, 0, 0, 0);
                    #pragma unroll
                    for (int r = 0; r < 4; ++r)
                        ts[(w * 32 + st * 16 + 4 * lg + r) * 80 + ei * 16 + l16] =
                            (bf16)(acc[r] + bcol[ei]);
                }
            }
            __syncthreads();
            bf16* out = (p == 0) ? Qb : Kb;
            #pragma unroll
            for (int i = 0; i < 4; ++i) {
                int idx = tid + i * 256;
                int r = idx >> 3, g = idx & 7;
                uint4 v = *(const uint4*)&ts[r * 80 + g * 8];
                *(uint4*)(out + (bh * S + s0 + r) * 64 + g * 8) = v;
            }
        } else {
            float brow[4];
            #pragma unroll
            for (int r = 0; r < 4; ++r)
                brow[r] = bias[h * 64 + w * 16 + 4 * lg + r];
            const int erow = w * 16 + l16;
            bf16x8 a0 = *(const bf16x8*)&Wl[erow][((lg    ) ^ (erow & 7)) * 8];
            bf16x8 a1 = *(const bf16x8*)&Wl[erow][((4 + lg) ^ (erow & 7)) * 8];
            #pragma unroll
            for (int st = 0; st < 8; ++st) {
                const int srow = st * 16 + l16;
                bf16x8 b0 = *(const bf16x8*)&xs[srow][((lg    ) ^ (srow & 7)) * 8];
                bf16x8 b1 = *(const bf16x8*)&xs[srow][((4 + lg) ^ (srow & 7)) * 8];
                f32x4 acc = {0.f, 0.f, 0.f, 0.f};
                acc = __builtin_amdgcn_mfma_f32_16x16x32_bf16(a0, b0, acc, 0, 0, 0);
                acc = __builtin_amdgcn_mfma_f32_16x16x32_bf16(a1, b1, acc, 0, 0, 0);
                #pragma unroll
                for (int r = 0; r < 4; ++r)
                    ts[(w * 16 + 4 * lg + r) * 136 + st * 16 + l16] =
                        (bf16)(acc[r] + brow[r]);
            }
            __syncthreads();
            #pragma unroll
            for (int i = 0; i < 4; ++i) {
                int idx = tid + i * 256;
                int r = idx >> 4, g = idx & 15;
                uint4 v = *(const uint4*)&ts[r * 136 + g * 8];
                *(uint4*)(Vt + (bh * 64 + r) * S + s0 + g * 8) = v;
            }
        }
    }
}

// ---------------------------------------------------------------------------
// Kernel 3: causal flash attention — R19-exact (measured 63.6 us):
// R17 schedule + T17 v_max3 tree.
// ---------------------------------------------------------------------------
__global__ __launch_bounds__(512) void attn(
    const bf16* __restrict__ Qb, const bf16* __restrict__ Kb,
    const bf16* __restrict__ Vt, bf16* __restrict__ ctx)
{
    const int lin = blockIdx.y * 8 + blockIdx.x;   // 0..1023
    const int bh  = lin & 63;                      // b*H + h
    const int qt  = 15 - (lin >> 6);               // heavy tiles dispatch first
    const int b = bh >> 4, h = bh & 15;
    const int tid = threadIdx.x;
    const int w = tid >> 6;          // warp 0..7
    const int l = tid & 63;
    const int l16 = l & 15, lg = l >> 4;

    __shared__ __align__(16) bf16 Kl[2][64][64];
    __shared__ __align__(16) bf16 Vl[2][64][64];
    __shared__ __align__(16) bf16 Pl[8][16][72];

    const bf16* Qp = Qb + (size_t)bh * S * 64;
    const bf16* Kp = Kb + (size_t)bh * S * 64;
    const bf16* Vp = Vt + (size_t)bh * 64 * S;

    const int str = tid >> 3;
    const int stc = tid & 7;
    const int sws = (stc ^ (str & 7)) * 8;

    int foff0[4], foff1[4];
    #pragma unroll
    for (int s = 0; s < 4; ++s) {
        foff0[s] = (16 * s + l16) * 64 + ((lg    ) ^ (l16 & 7)) * 8;
        foff1[s] = (16 * s + l16) * 64 + ((4 + lg) ^ (l16 & 7)) * 8;
    }
    bf16* Plw = &Pl[w][0][0];
    const int pwr = l16 * 72 + 4 * lg;         // P write col base (s adds 16s)
    const int prd = l16 * 72 + 8 * lg;         // P read offset (second +32)

    const bf16 one_ = (bf16)1.0f;
    const bf16x8 ones = {one_, one_, one_, one_, one_, one_, one_, one_};

    const int qw0  = qt * 128 + w * 16;
    const int qabs = qw0 + l16;
    const int nt   = 2 * qt + 2;

    bf16x8 qf0 = *(const bf16x8*)(Qp + (size_t)qabs * 64 + lg * 8);
    bf16x8 qf1 = *(const bf16x8*)(Qp + (size_t)qabs * 64 + 32 + lg * 8);

    f32x4 o[4] = {};
    float m_run = -1e30f, l_run = 0.f;

    {
        uint4 kreg = *(const uint4*)(Kp + (size_t)str * 64 + stc * 8);
        uint4 vreg = *(const uint4*)(Vp + (size_t)str * S + stc * 8);
        *(uint4*)&Kl[0][str][sws] = kreg;
        *(uint4*)&Vl[0][str][sws] = vreg;
    }
    int cur = 0;
    for (int t = 0; t < nt; ++t) {
        __syncthreads();
        const bool pfv = (t + 1 < nt);
        uint4 kreg, vreg;
        if (pfv) {                         // issue-early (T14)
            const int kv1 = (t + 1) * 64;
            kreg = *(const uint4*)(Kp + (size_t)(kv1 + str) * 64 + stc * 8);
            vreg = *(const uint4*)(Vp + (size_t)str * S + kv1 + stc * 8);
        }
        const int kv0 = t * 64;
        if (kv0 < qw0 + 16) {              // warp-uniform causal skip
            const bf16* Kbase = &Kl[cur][0][0];
            const bf16* Vbase = &Vl[cur][0][0];

            // ---- QK^T (swapped): S^T[kv][q], 8 MFMAs ----
            float p[16];
            __builtin_amdgcn_s_setprio(1);
            #pragma unroll
            for (int s = 0; s < 4; ++s) {
                f32x4 sc = {0.f, 0.f, 0.f, 0.f};
                bf16x8 ka = *(const bf16x8*)(Kbase + foff0[s]);
                bf16x8 kb = *(const bf16x8*)(Kbase + foff1[s]);
                sc = __builtin_amdgcn_mfma_f32_16x16x32_bf16(ka, qf0, sc, 0, 0, 0);
                sc = __builtin_amdgcn_mfma_f32_16x16x32_bf16(kb, qf1, sc, 0, 0, 0);
                p[4 * s + 0] = sc[0]; p[4 * s + 1] = sc[1];
                p[4 * s + 2] = sc[2]; p[4 * s + 3] = sc[3];
            }
            __builtin_amdgcn_s_setprio(0);

            // ---- causal mask (only warp-diagonal tiles) ----
            if (kv0 + 63 > qw0) {
                #pragma unroll
                for (int i = 0; i < 16; ++i) {
                    const int kvloc = 16 * (i >> 2) + 4 * lg + (i & 3);
                    if (kv0 + kvloc > qabs) p[i] = -1e30f;
                }
            }

            // ---- online softmax: lane-local defer-max, v_max3 tree ----
            const float a0 = max3(p[0],  p[1],  p[2]);
            const float a1 = max3(p[3],  p[4],  p[5]);
            const float a2 = max3(p[6],  p[7],  p[8]);
            const float a3 = max3(p[9],  p[10], p[11]);
            const float a4 = max3(p[12], p[13], p[14]);
            const float lmx = fmaxf(max3(a0, a1, a2), max3(a3, a4, p[15]));
            if (!__all(lmx <= m_run + DTHR)) {     // rare: rescale path
                float mx = fmaxf(lmx, __shfl_xor(lmx, 16));
                mx = fmaxf(mx, __shfl_xor(mx, 32));
                const float m_new = fmaxf(m_run, mx);
                const float corr = exp2_fast(m_run - m_new);
                l_run *= corr;
                #pragma unroll
                for (int ds = 0; ds < 4; ++ds) {
                    o[ds][0] *= corr; o[ds][1] *= corr;
                    o[ds][2] *= corr; o[ds][3] *= corr;
                }
                m_run = m_new;
            }
            #pragma unroll
            for (int i = 0; i < 16; ++i) p[i] = exp2_fast(p[i] - m_run);

            // ---- P -> per-warp LDS (bf16), then read PV B-frags ----
            #pragma unroll
            for (int s = 0; s < 4; ++s) {
                u32x2 pw;
                pw[0] = pk_bf16(p[4 * s + 0], p[4 * s + 1]);
                pw[1] = pk_bf16(p[4 * s + 2], p[4 * s + 3]);
                *(u32x2*)(Plw + pwr + 16 * s) = pw;
            }
            asm volatile("s_waitcnt lgkmcnt(0)" ::: "memory");
            bf16x8 pf0 = *(const bf16x8*)(Plw + prd);
            bf16x8 pf1 = *(const bf16x8*)(Plw + prd + 32);

            // ---- PV (swapped) + ones-row sum: 8 + 2 MFMAs ----
            __builtin_amdgcn_s_setprio(1);
            f32x4 o5 = {0.f, 0.f, 0.f, 0.f};
            o5 = __builtin_amdgcn_mfma_f32_16x16x32_bf16(ones, pf0, o5, 0, 0, 0);
            o5 = __builtin_amdgcn_mfma_f32_16x16x32_bf16(ones, pf1, o5, 0, 0, 0);
            #pragma unroll
            for (int ds = 0; ds < 4; ++ds) {
                bf16x8 v0 = *(const bf16x8*)(Vbase + foff0[ds]);
                bf16x8 v1 = *(const bf16x8*)(Vbase + foff1[ds]);
                o[ds] = __builtin_amdgcn_mfma_f32_16x16x32_bf16(v0, pf0, o[ds], 0, 0, 0);
                o[ds] = __builtin_amdgcn_mfma_f32_16x16x32_bf16(v1, pf1, o[ds], 0, 0, 0);
            }
            __builtin_amdgcn_s_setprio(0);
            l_run += o5[0];               // all 4 regs identical (ones rows)
        }
        if (pfv) {                         // write-late into other buffer
            *(uint4*)&Kl[cur ^ 1][str][sws] = kreg;
            *(uint4*)&Vl[cur ^ 1][str][sws] = vreg;
        }
        cur ^= 1;
    }

    const float il = 1.0f / l_run;
    bf16* crow = ctx + ((size_t)b * S + qabs) * E + h * 64;
    #pragma unroll
    for (int ds = 0; ds < 4; ++ds) {
        u32x2 pw;
        pw[0] = pk_bf16(o[ds][0] * il, o[ds][1] * il);
        pw[1] = pk_bf16(o[ds][2] * il, o[ds][3] * il);
        *(u32x2*)(crow + 16 * ds + 4 * lg) = pw;
    }
}

// ---------------------------------------------------------------------------
// Kernel 4: out = ctx[8192x1024] @ Wp[1024x1024] + bp, fp32 out.
// R18-exact (measured best ~12.5 us): 2-phase gl16 dbuf (64 KB LDS,
// 2 blocks/CU), XCD remap, direct scalar C-write. R19's 128KB LDS-staged
// epilogue REVERTED (halved occupancy, +8 us — m132 lesson, 3rd time).
// ---------------------------------------------------------------------------
__global__ __launch_bounds__(256) void out_gemm(
    const bf16* __restrict__ A, const bf16* __restrict__ Bt,
    const float* __restrict__ bp, float* __restrict__ C)
{
    const int lin = blockIdx.y * 8 + blockIdx.x;
    const int c   = lin & 7;
    const int k   = lin >> 3;
    const int n0  = (k & 7) * 128;
    const int m0  = (((k >> 3) << 3) | c) * 128;
    const int tid = threadIdx.x;
    const int w = tid >> 6, l = tid & 63;
    const int l16 = l & 15, lg = l >> 4;
    const int wm = w >> 1, wn = w & 1;

    __shared__ __align__(16) bf16 Al[2][128][64];   // 32 KB
    __shared__ __align__(16) bf16 Bl[2][128][64];   // 32 KB

    f32x4 acc[4][4] = {};

    const int r8 = l >> 3;
    const int chunk = ((l & 7) ^ r8) * 8;

    // prologue: DMA tile k0=0 into buffer 0
    #pragma unroll
    for (int i = 0; i < 4; ++i) {
        const int rb = 8 * w + 32 * i;
        gl16(A  + (size_t)(m0 + rb + r8) * E + chunk, &Al[0][rb][0]);
        gl16(Bt + (size_t)(n0 + rb + r8) * E + chunk, &Bl[0][rb][0]);
    }

    int cur = 0;
    for (int k0 = 0; k0 < E; k0 += 64) {
        __syncthreads();                    // buf[cur] DMA drained (vmcnt 0)
        if (k0 + 64 < E) {                  // DMA next tile into buf[cur^1]
            #pragma unroll
            for (int i = 0; i < 4; ++i) {
                const int rb = 8 * w + 32 * i;
                gl16(A  + (size_t)(m0 + rb + r8) * E + k0 + 64 + chunk,
                     &Al[cur ^ 1][rb][0]);
                gl16(Bt + (size_t)(n0 + rb + r8) * E + k0 + 64 + chunk,
                     &Bl[cur ^ 1][rb][0]);
            }
        }
        #pragma unroll
        for (int ks = 0; ks < 2; ++ks) {
            bf16x8 af[4], bfr[4];
            #pragma unroll
            for (int mi = 0; mi < 4; ++mi) {
                int r = wm * 64 + mi * 16 + l16;
                af[mi] = *(const bf16x8*)&Al[cur][r][((ks * 4 + lg) ^ (r & 7)) * 8];
            }
            #pragma unroll
            for (int ni = 0; ni < 4; ++ni) {
                int r = wn * 64 + ni * 16 + l16;
                bfr[ni] = *(const bf16x8*)&Bl[cur][r][((ks * 4 + lg) ^ (r & 7)) * 8];
            }
            #pragma unroll
            for (int mi = 0; mi < 4; ++mi)
                #pragma unroll
                for (int ni = 0; ni < 4; ++ni)
                    acc[mi][ni] = __builtin_amdgcn_mfma_f32_16x16x32_bf16(
                        af[mi], bfr[ni], acc[mi][ni], 0, 0, 0);
        }
        cur ^= 1;
    }

    #pragma unroll
    for (int ni = 0; ni < 4; ++ni) {
        const int col = n0 + wn * 64 + ni * 16 + l16;
        const float bias = bp[col];
        #pragma unroll
        for (int mi = 0; mi < 4; ++mi) {
            #pragma unroll
            for (int e = 0; e < 4; ++e) {
                int row = m0 + wm * 64 + mi * 16 + 4 * lg + e;
                C[(size_t)row * E + col] = acc[mi][ni][e] + bias;
            }
        }
    }
}

// ---------------------------------------------------------------------------
extern "C" void kernel_launch(void* const* d_in, const int* in_sizes, int n_in,
                              void* d_out, int out_size, void* d_ws, size_t ws_size,
                              hipStream_t stream)
{
    const float* xq = (const float*)d_in[0];
    const float* xk = (const float*)d_in[1];
    const float* xv = (const float*)d_in[2];
    const float* Wq = (const float*)d_in[3];
    const float* bq = (const float*)d_in[4];
    const float* Wk = (const float*)d_in[5];
    const float* bk = (const float*)d_in[6];
    const float* Wv = (const float*)d_in[7];
    const float* bv = (const float*)d_in[8];
    const float* Wp = (const float*)d_in[9];
    const float* bp = (const float*)d_in[10];
    float* out = (float*)d_out;

    char* ws = (char*)d_ws;
    const size_t sz_bhse = (size_t)B * H * S * HD;
    bf16* Qb  = (bf16*)ws;  ws += sz_bhse * 2;
    bf16* Kb  = (bf16*)ws;  ws += sz_bhse * 2;
    bf16* Vtw = (bf16*)ws;  ws += sz_bhse * 2;
    bf16* ctx = (bf16*)ws;  ws += (size_t)B * S * E * 2;
    bf16* Wpt = (bf16*)ws;  ws += (size_t)E * E * 2;
    bf16* Wt3 = (bf16*)ws;  ws += (size_t)3 * H * HD * HD * 2;

    prep_weights<<<dim3(16, 19), 256, 0, stream>>>(Wq, Wk, Wv, Wp, Wt3, Wpt);
    qkv_proj<<<dim3(S / 128, H, B), 256, 0, stream>>>(xq, xk, xv, Wt3,
                                                      bq, bk, bv, Qb, Kb, Vtw);
    attn<<<dim3(8, 128), 512, 0, stream>>>(Qb, Kb, Vtw, ctx);
    out_gemm<<<dim3(E / 128, (B * S) / 128), 256, 0, stream>>>(ctx, Wpt, bp, out);
}